// Round 1
// baseline (118.295 us; speedup 1.0000x reference)
//
#include <hip/hip_runtime.h>

#define NS 8192
#define EMBED 128
#define ROWCHUNK 512             // grid.y = 16 chunks of 512 rows
#define NPANEL (ROWCHUNK / 32)   // 16 panels of 32 rows
#define AROW 12                  // correction-hist row stride (11 bins + 1 pad)
#define INV64K (1.0f / 65536.0f)

typedef __bf16 bf16x8 __attribute__((ext_vector_type(8)));
typedef float f32x4 __attribute__((ext_vector_type(4)));
typedef float f32x2 __attribute__((ext_vector_type(2)));
typedef const __attribute__((address_space(1))) unsigned ag_u32;  // global
typedef __attribute__((address_space(3))) unsigned al_u32;        // LDS

// workspace layout (bytes from ws start)
#define OFF_XB  0u               // bf16 [8192][128] = 2 MiB (row-granule-XOR-swizzled)
#define OFF_GS  2097152u         // f32 [32][8192][4]  col-hist partials, bins 3..6 (4 MiB)
#define OFF_GSP 6291456u         // f32 [32][8192][4]  pos-hist partials (4 MiB)
#define OFF_GA  10485760u        // q16 [8192][12] all-hist corrections (atomic)
#define OFF_GAP 10878976u        // q16 [8192][12] pos-hist corrections (atomic)
#define OFF_CC  11272192u        // int  [128] class counts
#define OFF_AC  11272704u        // float[2] accum + u32 done
#define ZERO_BYTES 786960u       // OFF_GA .. end (16B multiple); gS/gSp fully overwritten

__device__ inline unsigned short f2bf(float f) {
  unsigned u = __float_as_uint(f);
  u += 0x7fffu + ((u >> 16) & 1u);   // round-to-nearest-even
  return (unsigned short)(u >> 16);
}
// v_med3_f32: 1-instr clamp (gfx950 has NO v_pk_min/max_f32 — packed min/max
// lowers to 2 scalar ops each, so med3-per-element is strictly cheaper)
__device__ inline float clamp01(float x) { return __builtin_amdgcn_fmed3f(x, 0.f, 1.f); }

// ---- prep: fp32->bf16 convert into XOR-swizzled layout + zero correction bufs ----
__global__ __launch_bounds__(256) void prep_kernel(const float* __restrict__ x,
                                                   unsigned short* __restrict__ xb,
                                                   uint4* __restrict__ zbase) {
  const int gid = blockIdx.x * 256 + threadIdx.x;   // 131072 threads: row*16+granule
  const int row = gid >> 4, g = gid & 15;
  const float4 v0 = reinterpret_cast<const float4*>(x)[row * 32 + g * 2];
  const float4 v1 = reinterpret_cast<const float4*>(x)[row * 32 + g * 2 + 1];
  uint4 o;
  o.x = (unsigned)f2bf(v0.x) | ((unsigned)f2bf(v0.y) << 16);
  o.y = (unsigned)f2bf(v0.z) | ((unsigned)f2bf(v0.w) << 16);
  o.z = (unsigned)f2bf(v1.x) | ((unsigned)f2bf(v1.y) << 16);
  o.w = (unsigned)f2bf(v1.z) | ((unsigned)f2bf(v1.w) << 16);
  reinterpret_cast<uint4*>(xb)[row * 16 + (g ^ (row & 7))] = o;
  if (gid < (int)(ZERO_BYTES / 16u)) zbase[gid] = make_uint4(0u, 0u, 0u, 0u);
}

// ---- main ----
// Wave layout: 4 waves = {col half w2 (32 cols, TWO reg B-frag sets)} x
// {row half wr (16 rows of each 32-row panel)}. One A-fragment read feeds both
// col sets (2x LDS-read reuse vs 16-col waves). Symmetry: per-row hist ==
// per-col hist, so each lane accumulates the hists of its TWO l16 cols.
// gS/gSp are plain per-(chunk,rowhalf) float4 stores (32 slots), no atomics.
__global__ __launch_bounds__(256, 4) void fastap_main_kernel(
    const unsigned short* __restrict__ xb,
    const int* __restrict__ labels,
    float* __restrict__ gS, float* __restrict__ gSp,
    unsigned* __restrict__ gA, unsigned* __restrict__ gAp,
    int* __restrict__ ccount) {
  __shared__ __align__(16) unsigned short sA[2][32 * 128];  // 2 x 8KB row panels
  __shared__ int sLab[ROWCHUNK];                            // this chunk's row labels

  const int tid  = threadIdx.x;
  const int wave = tid >> 6;
  const int lane = tid & 63;
  const int l16  = lane & 15;
  const int quad = lane >> 4;
  const int w2   = wave >> 1;                 // col half (32 cols)
  const int wr   = wave & 1;                  // row half (16 of 32 panel rows)
  const int colBase  = blockIdx.x * 64;       // 128 col strips
  const int rowChunk = blockIdx.y * ROWCHUNK; // 16 row chunks

  if (tid < ROWCHUNK / 4)
    reinterpret_cast<int4*>(sLab)[tid] =
        reinterpret_cast<const int4*>(labels + rowChunk)[tid];

  // two fixed B fragment sets: cols jbase+l16 and jbase+16+l16, K=128
  // (jcol&7 == l16&7 for both, so the granule XOR uses l16&7)
  bf16x8 bfr[2][4];
  int jcolv[2], labj[2];
  #pragma unroll
  for (int s = 0; s < 2; ++s) {
    const int jc = colBase + w2 * 32 + s * 16 + l16;
    jcolv[s] = jc;
    labj[s] = labels[jc];
    #pragma unroll
    for (int kb = 0; kb < 4; ++kb) {
      const int pg = (kb * 4 + quad) ^ (l16 & 7);
      bfr[s][kb] = *reinterpret_cast<const bf16x8*>(&xb[jc * 128 + pg * 8]);
    }
  }

  f32x2 C01[2], C23[2], Cp01[2], Cp23[2];
  #pragma unroll
  for (int s = 0; s < 2; ++s) {
    C01[s] = (f32x2){0.f, 0.f};  C23[s] = (f32x2){0.f, 0.f};
    Cp01[s] = (f32x2){0.f, 0.f}; Cp23[s] = (f32x2){0.f, 0.f};
  }

  // A-frag ds_read offsets: rows wr*16+l16 within the 32-row panel
  // ((wr*16+l16)&7 == l16&7, so swizzle XOR unchanged)
  int aOff[4];
  #pragma unroll
  for (int kb = 0; kb < 4; ++kb)
    aOff[kb] = (wr * 16 + l16) * 128 + (((kb * 4 + quad) ^ (l16 & 7)) << 3);

  // stage panel p's 32 rows (8KB) into buffer b: 2 x 16B per thread
  const unsigned short* xrb = xb + rowChunk * 128;
  auto stage = [&](int p, int b) {
    const unsigned short* src = xrb + p * (32 * 128);
    __builtin_amdgcn_global_load_lds((ag_u32*)(src + tid * 8),
                                     (al_u32*)(&sA[b][tid * 8]), 16, 0, 0);
    __builtin_amdgcn_global_load_lds((ag_u32*)(src + (tid + 256) * 8),
                                     (al_u32*)(&sA[b][(tid + 256) * 8]), 16, 0, 0);
  };

  // one 16-row x 32-col panel slice: A read once, two MFMA chains (col sets)
  auto panel = [&](const unsigned short* ap, int p) {
    const int4 lr = *reinterpret_cast<const int4*>(&sLab[p * 32 + wr * 16 + quad * 4]);
    bf16x8 a0 = *reinterpret_cast<const bf16x8*>(&ap[aOff[0]]);
    bf16x8 a1 = *reinterpret_cast<const bf16x8*>(&ap[aOff[1]]);
    bf16x8 a2 = *reinterpret_cast<const bf16x8*>(&ap[aOff[2]]);
    bf16x8 a3 = *reinterpret_cast<const bf16x8*>(&ap[aOff[3]]);
    f32x4 acc0 = {0.f, 0.f, 0.f, 0.f};
    f32x4 acc1 = {0.f, 0.f, 0.f, 0.f};
    acc0 = __builtin_amdgcn_mfma_f32_16x16x32_bf16(a0, bfr[0][0], acc0, 0, 0, 0);
    acc1 = __builtin_amdgcn_mfma_f32_16x16x32_bf16(a0, bfr[1][0], acc1, 0, 0, 0);
    acc0 = __builtin_amdgcn_mfma_f32_16x16x32_bf16(a1, bfr[0][1], acc0, 0, 0, 0);
    acc1 = __builtin_amdgcn_mfma_f32_16x16x32_bf16(a1, bfr[1][1], acc1, 0, 0, 0);
    acc0 = __builtin_amdgcn_mfma_f32_16x16x32_bf16(a2, bfr[0][2], acc0, 0, 0, 0);
    acc1 = __builtin_amdgcn_mfma_f32_16x16x32_bf16(a2, bfr[1][2], acc1, 0, 0, 0);
    acc0 = __builtin_amdgcn_mfma_f32_16x16x32_bf16(a3, bfr[0][3], acc0, 0, 0, 0);
    acc1 = __builtin_amdgcn_mfma_f32_16x16x32_bf16(a3, bfr[1][3], acc1, 0, 0, 0);

    const int labr[4] = {lr.x, lr.y, lr.z, lr.w};
    // fast path: pk_fma for the ramp, med3 per element for the clamp.
    // Register bins 3..6 are EXACT for all t: H[k] = clamp01(5a + (k-4)).
    #pragma unroll
    for (int r = 0; r < 4; ++r) {            // D: row = quad*4+r, col = l16 (per set)
      #pragma unroll
      for (int s = 0; s < 2; ++s) {
        const float a = (s == 0) ? acc0[r] : acc1[r];   // cos(i, jcol_s)
        const f32x2 av = {a, a};
        f32x2 d01 = __builtin_elementwise_fma(av, (f32x2){5.f, 5.f}, (f32x2){-1.f, 0.f});
        f32x2 d23 = __builtin_elementwise_fma(av, (f32x2){5.f, 5.f}, (f32x2){1.f, 2.f});
        d01 = (f32x2){clamp01(d01.x), clamp01(d01.y)};
        d23 = (f32x2){clamp01(d23.x), clamp01(d23.y)};
        C01[s] += d01; C23[s] += d23;
        const bool isPos = (labr[r] == labj[s]);
        if (__any(isPos)) {                  // positives ~1%: skip Cp wave-uniformly
          const float pm = isPos ? 1.f : 0.f;
          const f32x2 p2 = {pm, pm};
          Cp01[s] = __builtin_elementwise_fma(p2, d01, Cp01[s]);
          Cp23[s] = __builtin_elementwise_fma(p2, d23, Cp23[s]);
        }
      }
    }

    // one rare check per 8 pairs (abs modifiers free on v_max)
    const float m0 = fmaxf(fmaxf(fabsf(acc0[0]), fabsf(acc0[1])),
                           fmaxf(fabsf(acc0[2]), fabsf(acc0[3])));
    const float m1 = fmaxf(fmaxf(fabsf(acc1[0]), fabsf(acc1[1])),
                           fmaxf(fabsf(acc1[2]), fabsf(acc1[3])));
    if (__builtin_expect(fmaxf(m0, m1) > 0.4f, 0)) {
      #pragma unroll
      for (int s = 0; s < 2; ++s) {
        #pragma unroll
        for (int r = 0; r < 4; ++r) {
          const float a = (s == 0) ? acc0[r] : acc1[r];
          if (fabsf(a) <= 0.4f) continue;
          const int i = rowChunk + p * 32 + wr * 16 + quad * 4 + r;
          const int jc = jcolv[s];
          // recompute (bit-identical to fast path)
          const float d0 = clamp01(fmaf(a, 5.f, -1.f));
          const float d1 = clamp01(a * 5.f);
          const float d2 = clamp01(fmaf(a, 5.f, 1.f));
          const float d3 = clamp01(fmaf(a, 5.f, 2.f));
          if (i == jc) {
            // diagonal: cancel fast contributions (pm was 1) + bins>=7 base (+1)
            C01[s] -= (f32x2){d0, d1};  C23[s] -= (f32x2){d2, d3};
            Cp01[s] -= (f32x2){d0, d1}; Cp23[s] -= (f32x2){d2, d3};
            #pragma unroll
            for (int k = 7; k <= 10; ++k)
              atomicAdd(&gA[jc * AROW + k], (unsigned)(-65536));
          } else {
            const bool isPos = (labr[r] == labj[s]);
            const float t = fmaf(a, -5.f, 5.f);
            #pragma unroll
            for (int k = 0; k <= 2; ++k) {       // assumed cumulative 0
              const float v = clamp01((float)(k + 1) - t);
              const int q = (int)(v * 65536.f + 0.5f);
              if (q) {
                atomicAdd(&gA[jc * AROW + k], (unsigned)q);
                if (isPos) atomicAdd(&gAp[jc * AROW + k], (unsigned)q);
              }
            }
            #pragma unroll
            for (int k = 7; k <= 10; ++k) {      // assumed cumulative 1
              const float v = clamp01((float)(k + 1) - t) - 1.f;
              const int q = (int)(v * 65536.f - 0.5f);
              if (q) {
                atomicAdd(&gA[jc * AROW + k], (unsigned)q);
                if (isPos) atomicAdd(&gAp[jc * AROW + k], (unsigned)q);
              }
            }
          }
        }
      }
    }
  };

  stage(0, 0);
  __syncthreads();             // sLab visible + panel 0 drained

  // class counts: one col-strip per row-chunk counts its 512 rows
  if (blockIdx.x == 0) {
    for (int idx = tid; idx < ROWCHUNK; idx += 256)
      atomicAdd(&ccount[sLab[idx]], 1);
  }

  #pragma unroll 1
  for (int p = 0; p < NPANEL; ++p) {
    const int cur = p & 1;
    if (p + 1 < NPANEL) stage(p + 1, cur ^ 1);   // async DMA behind this panel
    panel(&sA[cur][0], p);
    __syncthreads();
  }

  // reduce across the 4 quads sharing each column (lane ^16, ^32)
  #pragma unroll
  for (int m = 16; m < 64; m <<= 1) {
    #pragma unroll
    for (int s = 0; s < 2; ++s) {
      C01[s].x  += __shfl_xor(C01[s].x,  m, 64); C01[s].y  += __shfl_xor(C01[s].y,  m, 64);
      C23[s].x  += __shfl_xor(C23[s].x,  m, 64); C23[s].y  += __shfl_xor(C23[s].y,  m, 64);
      Cp01[s].x += __shfl_xor(Cp01[s].x, m, 64); Cp01[s].y += __shfl_xor(Cp01[s].y, m, 64);
      Cp23[s].x += __shfl_xor(Cp23[s].x, m, 64); Cp23[s].y += __shfl_xor(Cp23[s].y, m, 64);
    }
  }

  if (quad == 0) {
    const int slot = blockIdx.y * 2 + wr;        // 32 partial slots, no atomics
    #pragma unroll
    for (int s = 0; s < 2; ++s) {
      const float4 cv  = make_float4(C01[s].x,  C01[s].y,  C23[s].x,  C23[s].y);
      const float4 cpv = make_float4(Cp01[s].x, Cp01[s].y, Cp23[s].x, Cp23[s].y);
      reinterpret_cast<float4*>(gS)[slot * NS + jcolv[s]]  = cv;
      reinterpret_cast<float4*>(gSp)[slot * NS + jcolv[s]] = cpv;
    }
  }
}

// ---- epilogue: sum 32 partials, per-row AP + final loss (last block finalizes) ----
__global__ __launch_bounds__(256) void epilogue_kernel(
    const float* __restrict__ gS, const float* __restrict__ gSp,
    const unsigned* __restrict__ gA, const unsigned* __restrict__ gAp,
    const int* __restrict__ labels, const int* __restrict__ ccount,
    float* __restrict__ accum, unsigned* __restrict__ done,
    float* __restrict__ out) {
  const int i = blockIdx.x * 256 + threadIdx.x;
  const int np = ccount[labels[i]] - 1;   // N_pos = classCount - 1
  const float4* gS4  = reinterpret_cast<const float4*>(gS);
  const float4* gSp4 = reinterpret_cast<const float4*>(gSp);
  float4 Cs  = make_float4(0.f, 0.f, 0.f, 0.f);
  float4 Cps = make_float4(0.f, 0.f, 0.f, 0.f);
  #pragma unroll 8
  for (int c = 0; c < 32; ++c) {
    const float4 u = gS4[c * NS + i];
    const float4 v = gSp4[c * NS + i];
    Cs.x += u.x; Cs.y += u.y; Cs.z += u.z; Cs.w += u.w;
    Cps.x += v.x; Cps.y += v.y; Cps.z += v.z; Cps.w += v.w;
  }
  const float CsA[4]  = {Cs.x, Cs.y, Cs.z, Cs.w};
  const float CpsA[4] = {Cps.x, Cps.y, Cps.z, Cps.w};

  float ap = 0.f, val = 0.f, HpPrev = 0.f;
  #pragma unroll
  for (int b = 0; b <= 10; ++b) {
    const float baseH  = (b < 3) ? 0.f : (b < 7) ? CsA[b - 3]  : 8192.f;
    const float basePp = (b < 3) ? 0.f : (b < 7) ? CpsA[b - 3] : (float)np;
    const float H  = baseH  + (float)(int)gA[i * AROW + b]  * INV64K;
    const float Hp = basePp + (float)(int)gAp[i * AROW + b] * INV64K;
    const float hp = Hp - HpPrev;
    HpPrev = Hp;
    if (H > 1e-6f) ap += hp * Hp / H;
  }
  if (np > 0) { ap /= (float)np; val = 1.f; } else ap = 0.f;

  __shared__ float sa[256], sv[256];
  sa[threadIdx.x] = ap; sv[threadIdx.x] = val;
  __syncthreads();
  for (int s = 128; s > 0; s >>= 1) {
    if (threadIdx.x < s) {
      sa[threadIdx.x] += sa[threadIdx.x + s];
      sv[threadIdx.x] += sv[threadIdx.x + s];
    }
    __syncthreads();
  }
  if (threadIdx.x == 0) {
    atomicAdd(&accum[0], sa[0]);
    atomicAdd(&accum[1], sv[0]);
    __threadfence();
    const unsigned prev = atomicAdd(done, 1u);
    if (prev == gridDim.x - 1) {
      const float a = atomicAdd(&accum[0], 0.f);   // coherent reads
      const float c = atomicAdd(&accum[1], 0.f);
      out[0] = 1.f - (c > 0.f ? a / c : 0.f);
    }
  }
}

extern "C" void kernel_launch(void* const* d_in, const int* in_sizes, int n_in,
                              void* d_out, int out_size, void* d_ws, size_t ws_size,
                              hipStream_t stream) {
  const float* x      = (const float*)d_in[0];
  const int*   labels = (const int*)d_in[1];
  float* out = (float*)d_out;

  char* ws = (char*)d_ws;
  unsigned short* xb = (unsigned short*)(ws + OFF_XB);
  float*    gS   = (float*)(ws + OFF_GS);
  float*    gSp  = (float*)(ws + OFF_GSP);
  unsigned* gA   = (unsigned*)(ws + OFF_GA);
  unsigned* gAp  = (unsigned*)(ws + OFF_GAP);
  int*      cc   = (int*)(ws + OFF_CC);
  float*    accum = (float*)(ws + OFF_AC);
  unsigned* done  = (unsigned*)(ws + OFF_AC + 8);

  prep_kernel<<<512, 256, 0, stream>>>(x, xb, (uint4*)(ws + OFF_GA));
  fastap_main_kernel<<<dim3(NS / 64, NS / ROWCHUNK), 256, 0, stream>>>(
      xb, labels, gS, gSp, gA, gAp, cc);
  epilogue_kernel<<<NS / 256, 256, 0, stream>>>(gS, gSp, gA, gAp, labels, cc,
                                                accum, done, out);
}

// Round 2
// 111.327 us; speedup vs baseline: 1.0626x; 1.0626x over previous
//
#include <hip/hip_runtime.h>

#define NS 8192
#define EMBED 128
#define ROWCHUNK 512             // grid.y = 16 chunks of 512 rows
#define NPANEL (ROWCHUNK / 32)   // 16 panels of 32 rows
#define AROW 12                  // correction-hist row stride (11 bins + 1 pad)
#define INV64K (1.0f / 65536.0f)

typedef __bf16 bf16x8 __attribute__((ext_vector_type(8)));
typedef float f32x4 __attribute__((ext_vector_type(4)));
typedef float f32x2 __attribute__((ext_vector_type(2)));
typedef const __attribute__((address_space(1))) unsigned ag_u32;  // global
typedef __attribute__((address_space(3))) unsigned al_u32;        // LDS

// workspace layout (bytes from ws start)
#define OFF_XB  0u               // bf16 [8192][128] = 2 MiB (row-granule-XOR-swizzled)
#define OFF_GS  2097152u         // f32 [16][8192][4]  col-hist partials, bins 3..6 (2 MiB)
#define OFF_GSP 4194304u         // f32 [16][8192][4]  pos-hist partials (2 MiB)
#define OFF_GA  6291456u         // q16 [8192][12] all-hist corrections (atomic)
#define OFF_GAP 6684672u         // q16 [8192][12] pos-hist corrections (atomic)
#define OFF_CC  7077888u         // int  [128] class counts
#define OFF_AC  7078400u         // float[2] accum + u32 done
#define ZERO_BYTES 786960u       // OFF_GA .. end (16B multiple); gS/gSp fully overwritten

__device__ inline unsigned short f2bf(float f) {
  unsigned u = __float_as_uint(f);
  u += 0x7fffu + ((u >> 16) & 1u);   // round-to-nearest-even
  return (unsigned short)(u >> 16);
}
// v_med3_f32 with inline consts: 1-instr clamp. gfx950 has NO v_pk_min/max_f32,
// so the old packed min+max clamp was 4 scalar ops per f32x2; this is 2.
__device__ inline float clamp01(float x) { return __builtin_amdgcn_fmed3f(x, 0.f, 1.f); }

// ---- prep: fp32->bf16 convert into XOR-swizzled layout + zero correction bufs ----
__global__ __launch_bounds__(256) void prep_kernel(const float* __restrict__ x,
                                                   unsigned short* __restrict__ xb,
                                                   uint4* __restrict__ zbase) {
  const int gid = blockIdx.x * 256 + threadIdx.x;   // 131072 threads: row*16+granule
  const int row = gid >> 4, g = gid & 15;
  const float4 v0 = reinterpret_cast<const float4*>(x)[row * 32 + g * 2];
  const float4 v1 = reinterpret_cast<const float4*>(x)[row * 32 + g * 2 + 1];
  uint4 o;
  o.x = (unsigned)f2bf(v0.x) | ((unsigned)f2bf(v0.y) << 16);
  o.y = (unsigned)f2bf(v0.z) | ((unsigned)f2bf(v0.w) << 16);
  o.z = (unsigned)f2bf(v1.x) | ((unsigned)f2bf(v1.y) << 16);
  o.w = (unsigned)f2bf(v1.z) | ((unsigned)f2bf(v1.w) << 16);
  reinterpret_cast<uint4*>(xb)[row * 16 + (g ^ (row & 7))] = o;
  if (gid < (int)(ZERO_BYTES / 16u)) zbase[gid] = make_uint4(0u, 0u, 0u, 0u);
}

// ---- main: fixed 16-col B frags per wave, streamed 32-row LDS panels ----
// Symmetry: per-row hist == per-col hist, so each lane accumulates the hist of
// ONE column (its l16 col) across its 4 acc rows -> packed C01/C23, Cp01/Cp23.
// gS/gSp are plain per-row-chunk float4 stores (16 slots), no atomics.
__global__ __launch_bounds__(256, 8) void fastap_main_kernel(
    const unsigned short* __restrict__ xb,
    const int* __restrict__ labels,
    float* __restrict__ gS, float* __restrict__ gSp,
    unsigned* __restrict__ gA, unsigned* __restrict__ gAp,
    int* __restrict__ ccount) {
  __shared__ __align__(16) unsigned short sA[2][32 * 128];  // 2 x 8KB row panels
  __shared__ int sLab[ROWCHUNK];                            // this chunk's row labels

  const int tid  = threadIdx.x;
  const int wave = tid >> 6;
  const int lane = tid & 63;
  const int l16  = lane & 15;
  const int quad = lane >> 4;
  const int colBase  = blockIdx.x * 64;       // 128 col strips
  const int rowChunk = blockIdx.y * ROWCHUNK; // 16 row chunks

  if (tid < ROWCHUNK / 4)
    reinterpret_cast<int4*>(sLab)[tid] =
        reinterpret_cast<const int4*>(labels + rowChunk)[tid];

  // fixed B fragments: this wave's 16 cols, K=128 (jcol&7 == l16&7)
  const int jcol = colBase + wave * 16 + l16;
  bf16x8 bfr[4];
  #pragma unroll
  for (int kb = 0; kb < 4; ++kb) {
    const int pg = (kb * 4 + quad) ^ (l16 & 7);
    bfr[kb] = *reinterpret_cast<const bf16x8*>(&xb[jcol * 128 + pg * 8]);
  }
  const int labj = labels[jcol];

  f32x2 C01 = {0.f, 0.f}, C23 = {0.f, 0.f};
  f32x2 Cp01 = {0.f, 0.f}, Cp23 = {0.f, 0.f};

  // A-frag ds_read offsets within a 16-row sub-panel (row&7 == l16&7)
  int aOff[4];
  #pragma unroll
  for (int kb = 0; kb < 4; ++kb)
    aOff[kb] = l16 * 128 + (((kb * 4 + quad) ^ (l16 & 7)) << 3);

  // stage panel p's 32 rows (8KB) into buffer b: 2 x 16B per thread
  const unsigned short* xrb = xb + rowChunk * 128;
  auto stage = [&](int p, int b) {
    const unsigned short* src = xrb + p * (32 * 128);
    __builtin_amdgcn_global_load_lds((ag_u32*)(src + tid * 8),
                                     (al_u32*)(&sA[b][tid * 8]), 16, 0, 0);
    __builtin_amdgcn_global_load_lds((ag_u32*)(src + (tid + 256) * 8),
                                     (al_u32*)(&sA[b][(tid + 256) * 8]), 16, 0, 0);
  };

  // one 16-row x 16-col tile; lcr = row offset within chunk (mult of 16)
  auto tile16 = [&](const unsigned short* ap, int lcr) {
    const int4 lr = *reinterpret_cast<const int4*>(&sLab[lcr + quad * 4]);
    bf16x8 a0 = *reinterpret_cast<const bf16x8*>(&ap[aOff[0]]);
    bf16x8 a1 = *reinterpret_cast<const bf16x8*>(&ap[aOff[1]]);
    bf16x8 a2 = *reinterpret_cast<const bf16x8*>(&ap[aOff[2]]);
    bf16x8 a3 = *reinterpret_cast<const bf16x8*>(&ap[aOff[3]]);
    f32x4 acc = {0.f, 0.f, 0.f, 0.f};    // single chain: 8 waves/SIMD hide latency
    acc = __builtin_amdgcn_mfma_f32_16x16x32_bf16(a0, bfr[0], acc, 0, 0, 0);
    acc = __builtin_amdgcn_mfma_f32_16x16x32_bf16(a1, bfr[1], acc, 0, 0, 0);
    acc = __builtin_amdgcn_mfma_f32_16x16x32_bf16(a2, bfr[2], acc, 0, 0, 0);
    acc = __builtin_amdgcn_mfma_f32_16x16x32_bf16(a3, bfr[3], acc, 0, 0, 0);

    const int labr[4] = {lr.x, lr.y, lr.z, lr.w};
    // fast path: pk_fma ramps + med3 clamps. Register bins 3..6 are EXACT
    // for all t: H[k] = clamp01(5a + (k-4)).
    #pragma unroll
    for (int r = 0; r < 4; ++r) {              // D: row = quad*4+r, col = l16
      const float a = acc[r];                  // cos(i, jcol)
      const float pm = (labr[r] == labj) ? 1.f : 0.f;  // diag fixed in rare path
      const f32x2 av = {a, a}, p2 = {pm, pm};
      f32x2 d01 = __builtin_elementwise_fma(av, (f32x2){5.f, 5.f},
                                            (f32x2){-1.f, 0.f});
      f32x2 d23 = __builtin_elementwise_fma(av, (f32x2){5.f, 5.f},
                                            (f32x2){1.f, 2.f});
      d01 = (f32x2){clamp01(d01.x), clamp01(d01.y)};
      d23 = (f32x2){clamp01(d23.x), clamp01(d23.y)};
      C01 += d01; C23 += d23;
      Cp01 = __builtin_elementwise_fma(p2, d01, Cp01);
      Cp23 = __builtin_elementwise_fma(p2, d23, Cp23);
    }

    // one rare check per 4 pairs (abs modifiers are free on v_max)
    const float mabs = fmaxf(fmaxf(fabsf(acc[0]), fabsf(acc[1])),
                             fmaxf(fabsf(acc[2]), fabsf(acc[3])));
    if (__builtin_expect(mabs > 0.4f, 0)) {
      #pragma unroll
      for (int r = 0; r < 4; ++r) {
        const float a = acc[r];
        if (fabsf(a) <= 0.4f) continue;
        const int i = rowChunk + lcr + quad * 4 + r;
        // recompute (bit-identical to fast path)
        const float d0 = clamp01(fmaf(a, 5.f, -1.f));
        const float d1 = clamp01(a * 5.f);
        const float d2 = clamp01(fmaf(a, 5.f, 1.f));
        const float d3 = clamp01(fmaf(a, 5.f, 2.f));
        if (i == jcol) {
          // diagonal: cancel fast contributions (pm was 1) + bins>=7 base (+1)
          C01 -= (f32x2){d0, d1};  C23 -= (f32x2){d2, d3};
          Cp01 -= (f32x2){d0, d1}; Cp23 -= (f32x2){d2, d3};
          #pragma unroll
          for (int k = 7; k <= 10; ++k)
            atomicAdd(&gA[jcol * AROW + k], (unsigned)(-65536));
        } else {
          const bool isPos = (labr[r] == labj);
          const float t = fmaf(a, -5.f, 5.f);
          #pragma unroll
          for (int k = 0; k <= 2; ++k) {       // assumed cumulative 0
            const float v = clamp01((float)(k + 1) - t);
            const int q = (int)(v * 65536.f + 0.5f);
            if (q) {
              atomicAdd(&gA[jcol * AROW + k], (unsigned)q);
              if (isPos) atomicAdd(&gAp[jcol * AROW + k], (unsigned)q);
            }
          }
          #pragma unroll
          for (int k = 7; k <= 10; ++k) {      // assumed cumulative 1
            const float v = clamp01((float)(k + 1) - t) - 1.f;
            const int q = (int)(v * 65536.f - 0.5f);
            if (q) {
              atomicAdd(&gA[jcol * AROW + k], (unsigned)q);
              if (isPos) atomicAdd(&gAp[jcol * AROW + k], (unsigned)q);
            }
          }
        }
      }
    }
  };

  stage(0, 0);
  __syncthreads();             // sLab visible + panel 0 drained

  // class counts: one col-strip per row-chunk counts its 512 rows
  if (blockIdx.x == 0) {
    for (int idx = tid; idx < ROWCHUNK; idx += 256)
      atomicAdd(&ccount[sLab[idx]], 1);
  }

  #pragma unroll 1
  for (int p = 0; p < NPANEL; ++p) {
    const int cur = p & 1;
    if (p + 1 < NPANEL) stage(p + 1, cur ^ 1);   // async DMA behind this panel
    tile16(&sA[cur][0],        p * 32);
    tile16(&sA[cur][16 * 128], p * 32 + 16);
    __syncthreads();
  }

  // reduce across the 4 quads sharing each column (lane ^16, ^32)
  #pragma unroll
  for (int m = 16; m < 64; m <<= 1) {
    C01.x  += __shfl_xor(C01.x,  m, 64); C01.y  += __shfl_xor(C01.y,  m, 64);
    C23.x  += __shfl_xor(C23.x,  m, 64); C23.y  += __shfl_xor(C23.y,  m, 64);
    Cp01.x += __shfl_xor(Cp01.x, m, 64); Cp01.y += __shfl_xor(Cp01.y, m, 64);
    Cp23.x += __shfl_xor(Cp23.x, m, 64); Cp23.y += __shfl_xor(Cp23.y, m, 64);
  }

  if (quad == 0) {
    const int slot = blockIdx.y;                 // 16 partial slots, no atomics
    const float4 cv  = make_float4(C01.x,  C01.y,  C23.x,  C23.y);
    const float4 cpv = make_float4(Cp01.x, Cp01.y, Cp23.x, Cp23.y);
    reinterpret_cast<float4*>(gS)[slot * NS + jcol]  = cv;
    reinterpret_cast<float4*>(gSp)[slot * NS + jcol] = cpv;
  }
}

// ---- epilogue: sum 16 partials, per-row AP + final loss (last block finalizes) ----
__global__ __launch_bounds__(256) void epilogue_kernel(
    const float* __restrict__ gS, const float* __restrict__ gSp,
    const unsigned* __restrict__ gA, const unsigned* __restrict__ gAp,
    const int* __restrict__ labels, const int* __restrict__ ccount,
    float* __restrict__ accum, unsigned* __restrict__ done,
    float* __restrict__ out) {
  const int i = blockIdx.x * 256 + threadIdx.x;
  const int np = ccount[labels[i]] - 1;   // N_pos = classCount - 1
  const float4* gS4  = reinterpret_cast<const float4*>(gS);
  const float4* gSp4 = reinterpret_cast<const float4*>(gSp);
  float4 Cs  = make_float4(0.f, 0.f, 0.f, 0.f);
  float4 Cps = make_float4(0.f, 0.f, 0.f, 0.f);
  #pragma unroll 4
  for (int c = 0; c < 16; ++c) {
    const float4 u = gS4[c * NS + i];
    const float4 v = gSp4[c * NS + i];
    Cs.x += u.x; Cs.y += u.y; Cs.z += u.z; Cs.w += u.w;
    Cps.x += v.x; Cps.y += v.y; Cps.z += v.z; Cps.w += v.w;
  }
  const float CsA[4]  = {Cs.x, Cs.y, Cs.z, Cs.w};
  const float CpsA[4] = {Cps.x, Cps.y, Cps.z, Cps.w};

  float ap = 0.f, val = 0.f, HpPrev = 0.f;
  #pragma unroll
  for (int b = 0; b <= 10; ++b) {
    const float baseH  = (b < 3) ? 0.f : (b < 7) ? CsA[b - 3]  : 8192.f;
    const float basePp = (b < 3) ? 0.f : (b < 7) ? CpsA[b - 3] : (float)np;
    const float H  = baseH  + (float)(int)gA[i * AROW + b]  * INV64K;
    const float Hp = basePp + (float)(int)gAp[i * AROW + b] * INV64K;
    const float hp = Hp - HpPrev;
    HpPrev = Hp;
    if (H > 1e-6f) ap += hp * Hp / H;
  }
  if (np > 0) { ap /= (float)np; val = 1.f; } else ap = 0.f;

  __shared__ float sa[256], sv[256];
  sa[threadIdx.x] = ap; sv[threadIdx.x] = val;
  __syncthreads();
  for (int s = 128; s > 0; s >>= 1) {
    if (threadIdx.x < s) {
      sa[threadIdx.x] += sa[threadIdx.x + s];
      sv[threadIdx.x] += sv[threadIdx.x + s];
    }
    __syncthreads();
  }
  if (threadIdx.x == 0) {
    atomicAdd(&accum[0], sa[0]);
    atomicAdd(&accum[1], sv[0]);
    __threadfence();
    const unsigned prev = atomicAdd(done, 1u);
    if (prev == gridDim.x - 1) {
      const float a = atomicAdd(&accum[0], 0.f);   // coherent reads
      const float c = atomicAdd(&accum[1], 0.f);
      out[0] = 1.f - (c > 0.f ? a / c : 0.f);
    }
  }
}

extern "C" void kernel_launch(void* const* d_in, const int* in_sizes, int n_in,
                              void* d_out, int out_size, void* d_ws, size_t ws_size,
                              hipStream_t stream) {
  const float* x      = (const float*)d_in[0];
  const int*   labels = (const int*)d_in[1];
  float* out = (float*)d_out;

  char* ws = (char*)d_ws;
  unsigned short* xb = (unsigned short*)(ws + OFF_XB);
  float*    gS   = (float*)(ws + OFF_GS);
  float*    gSp  = (float*)(ws + OFF_GSP);
  unsigned* gA   = (unsigned*)(ws + OFF_GA);
  unsigned* gAp  = (unsigned*)(ws + OFF_GAP);
  int*      cc   = (int*)(ws + OFF_CC);
  float*    accum = (float*)(ws + OFF_AC);
  unsigned* done  = (unsigned*)(ws + OFF_AC + 8);

  prep_kernel<<<512, 256, 0, stream>>>(x, xb, (uint4*)(ws + OFF_GA));
  fastap_main_kernel<<<dim3(NS / 64, NS / ROWCHUNK), 256, 0, stream>>>(
      xb, labels, gS, gSp, gA, gAp, cc);
  epilogue_kernel<<<NS / 256, 256, 0, stream>>>(gS, gSp, gA, gAp, labels, cc,
                                                accum, done, out);
}